// Round 5
// baseline (255.141 us; speedup 1.0000x reference)
//
#include <hip/hip_runtime.h>
#include <math.h>

// Problem constants
#define R_ 5
#define NN 68        // N_NODES == LATENT
#define KK 32        // neighbors per node
#define NL 3         // GCN layers
#define LAT 68
#define ROWQ (NN / 4)        // 17 float4 per node row
#define NF4 ((NN * NN) / 4)  // 1156 float4 per output row
#define BBK2 16              // batches per K2 block
#define LSTR 344             // LDS row stride (floats) for K2, 16B-aligned

// ---------------- P1: densify GCN weights ----------------
// W'[m][n] = sum_{k: adj[n,k]==m} gw[n,k]  (exact rewrite of the gather)
__global__ __launch_bounds__(128) void densify_k(
    const int* __restrict__ adj, const float* __restrict__ gw,
    float* __restrict__ wd) {
  const int rl = blockIdx.x;  // r*NL + l in 0..14
  const int t = threadIdx.x;
  __shared__ float col[NN][NN + 4];
  for (int i = t; i < NN * (NN + 4); i += 128) (&col[0][0])[i] = 0.0f;
  __syncthreads();
  if (t < NN) {
    const int n = t;  // thread owns column n -> no races
    const int* ar = adj + n * KK;
    const float* wr = gw + ((size_t)rl * NN + n) * KK;
    for (int k = 0; k < KK; ++k) col[ar[k]][n] += wr[k];
  }
  __syncthreads();
  float* wout = wd + (size_t)rl * NN * NN;  // [m][n], n contiguous
  for (int i = t; i < NN * NN; i += 128) {
    const int m = i / NN, n = i - m * NN;
    wout[i] = col[m][n];
  }
}

// ---------------- P2: transpose z -> zT[l][b] ----------------
__global__ __launch_bounds__(256) void ztr_k(const float* __restrict__ z,
                                             float* __restrict__ zT, int B) {
  const int t = threadIdx.x;
  const int b0 = blockIdx.x * 64;
  __shared__ float zls[64][LAT + 1];  // +1: stride 69 -> conflict-free both ways
  for (int idx = t; idx < 64 * ROWQ; idx += 256) {
    const int row = idx / ROWQ, q = idx - row * ROWQ;
    const float4 v =
        *reinterpret_cast<const float4*>(z + (size_t)(b0 + row) * LAT + 4 * q);
    zls[row][4 * q + 0] = v.x;
    zls[row][4 * q + 1] = v.y;
    zls[row][4 * q + 2] = v.z;
    zls[row][4 * q + 3] = v.w;
  }
  __syncthreads();
  for (int idx = t; idx < LAT * 64; idx += 256) {
    const int l = idx >> 6, bb = idx & 63;
    zT[(size_t)l * B + b0 + bb] = zls[bb][l];
  }
}

// ---------------- K1: GEMM-chain, 4-wave blocks, node-split ----------------
// Block = (channel r, 64-batch group), 256 threads. lane = batch; wave w owns
// float4-columns [4w, 4w+cnt) of the 17 (wave 3 takes 5). Per m-iter a wave
// issues 4-5 uniform b128 weight loads + ~17 FMAs; 5 blocks/CU = 20 waves/CU
// (vs 5 in v4) for latency hiding. Single xs buffer: read->bar->write->bar.
__global__ __launch_bounds__(256) void chain_k(
    const float* __restrict__ zT, const float* __restrict__ fc_w,
    const float* __restrict__ fc_b, const float* __restrict__ wd,
    const float* __restrict__ gb, float* __restrict__ X, int B, int nb) {
  const int t = threadIdx.x;
  const int lane = t & 63;
  const int w = t >> 6;                 // wave 0..3
  const int jbase = w * 4;              // first float4-column owned
  const int cnt = (w == 3) ? 5 : 4;     // float4-columns owned
  const int r = blockIdx.x / nb;
  const int b0 = (blockIdx.x - r * nb) * 64;

  __shared__ float xs[NN][64];          // 17.4 KB; holds z, then x per stage
  float4 acc[5];                        // statically indexed (j compile-time)

  // stage zT rows for this batch group (coalesced; same addrs across r-blocks)
  for (int idx = t; idx < NN * 64; idx += 256) {
    const int m = idx >> 6;
    xs[m][idx & 63] = zT[(size_t)m * B + b0 + (idx & 63)];
  }
  __syncthreads();

  // ---- 4 stages: fc (no sigmoid), then 3 GCN layers (sigmoid) ----
#pragma unroll 1
  for (int stage = 0; stage < 1 + NL; ++stage) {
    const float* wb;
    const float* bias;
    if (stage == 0) {
      wb = fc_w + (size_t)r * LAT * NN;
      bias = fc_b + r * NN;
    } else {
      wb = wd + (size_t)(r * NL + (stage - 1)) * NN * NN;
      bias = gb + (size_t)(r * NL + (stage - 1)) * NN;
    }
    const float4* b4 = reinterpret_cast<const float4*>(bias) + jbase;
#pragma unroll
    for (int j = 0; j < 5; ++j)
      if (j < cnt) acc[j] = b4[j];

#pragma unroll 2
    for (int m = 0; m < NN; ++m) {
      const float xm = xs[m][lane];  // stride-1 across lanes, conflict-free
      const float4* w4 = reinterpret_cast<const float4*>(wb + m * NN) + jbase;
#pragma unroll
      for (int j = 0; j < 5; ++j) {
        if (j < cnt) {
          const float4 ww = w4[j];  // wave-uniform -> scalar load
          acc[j].x = fmaf(xm, ww.x, acc[j].x);
          acc[j].y = fmaf(xm, ww.y, acc[j].y);
          acc[j].z = fmaf(xm, ww.z, acc[j].z);
          acc[j].w = fmaf(xm, ww.w, acc[j].w);
        }
      }
    }
    if (stage > 0) {  // sigmoid
#pragma unroll
      for (int j = 0; j < 5; ++j) {
        if (j < cnt) {
          acc[j].x = 1.0f / (1.0f + __expf(-acc[j].x));
          acc[j].y = 1.0f / (1.0f + __expf(-acc[j].y));
          acc[j].z = 1.0f / (1.0f + __expf(-acc[j].z));
          acc[j].w = 1.0f / (1.0f + __expf(-acc[j].w));
        }
      }
    }
    if (stage < NL) {
      __syncthreads();  // all reads of old xs complete (consumed into acc)
#pragma unroll
      for (int j = 0; j < 5; ++j) {
        if (j < cnt) {
          const int n0 = 4 * (jbase + j);
          xs[n0 + 0][lane] = acc[j].x;
          xs[n0 + 1][lane] = acc[j].y;
          xs[n0 + 2][lane] = acc[j].z;
          xs[n0 + 3][lane] = acc[j].w;
        }
      }
      __syncthreads();
    }
  }

  // ---- final X -> ws, layout [r*68+n][b]: coalesced 256B rows ----
  float* Xb = X + (size_t)r * NN * B + b0 + lane;
#pragma unroll
  for (int j = 0; j < 5; ++j) {
    if (j < cnt) {
      const int n0 = 4 * (jbase + j);
      Xb[(size_t)(n0 + 0) * B] = acc[j].x;
      Xb[(size_t)(n0 + 1) * B] = acc[j].y;
      Xb[(size_t)(n0 + 2) * B] = acc[j].z;
      Xb[(size_t)(n0 + 3) * B] = acc[j].w;
    }
  }
}

// ---------------- K2: outer product + store (streaming) ----------------
__global__ __launch_bounds__(256) void outer_k(const float* __restrict__ X,
                                               float* __restrict__ out, int B) {
  const int t = threadIdx.x;
  const int b0 = blockIdx.x * BBK2;
  __shared__ float xls[BBK2 * LSTR];

  // stage X[rn][b0..b0+15] -> xls[bb][rn]; reads are exact 64B lines
  for (int idx = t; idx < R_ * NN * BBK2; idx += 256) {
    const int rn = idx >> 4, bb = idx & (BBK2 - 1);
    xls[bb * LSTR + rn] = X[(size_t)rn * B + b0 + bb];
  }
  __syncthreads();

  float4* ob = reinterpret_cast<float4*>(out) + (size_t)b0 * NF4;
  const int total = BBK2 * NF4;  // 18496
  for (int fg = t; fg < total; fg += 256) {
    const int bb = fg / NF4;
    const int f = fg - bb * NF4;
    const int i = f / ROWQ;
    const int q = f - i * ROWQ;
    const float* xb = &xls[bb * LSTR];
    float4 a = make_float4(0.f, 0.f, 0.f, 0.f);
#pragma unroll
    for (int r = 0; r < R_; ++r) {
      const float xi = xb[r * NN + i];
      const float4 xj = *reinterpret_cast<const float4*>(xb + r * NN + 4 * q);
      a.x = fmaf(xi, xj.x, a.x);
      a.y = fmaf(xi, xj.y, a.y);
      a.z = fmaf(xi, xj.z, a.z);
      a.w = fmaf(xi, xj.w, a.w);
    }
    ob[fg] = a;  // lanes consecutive -> perfectly coalesced
  }
}

extern "C" void kernel_launch(void* const* d_in, const int* in_sizes, int n_in,
                              void* d_out, int out_size, void* d_ws, size_t ws_size,
                              hipStream_t stream) {
  const float* z    = (const float*)d_in[0];  // (16384, 68)
  const int*   adj  = (const int*)  d_in[1];  // (68, 32)
  const float* fc_w = (const float*)d_in[2];  // (5, 68, 68)
  const float* fc_b = (const float*)d_in[3];  // (5, 68)
  const float* gw   = (const float*)d_in[4];  // (5, 3, 68, 32)
  const float* gb   = (const float*)d_in[5];  // (5, 3, 68)
  float* out = (float*)d_out;                 // (16384, 4624)

  const int B = in_sizes[0] / LAT;            // 16384
  // ws layout (f32): wd[15*68*68] | zT[68*B] | X[340*B]  (~27.1 MB total)
  float* wd = (float*)d_ws;
  float* zT = wd + R_ * NL * NN * NN;
  float* X  = zT + (size_t)LAT * B;

  const int nb = B / 64;                      // 256 batch-groups

  densify_k<<<R_ * NL, 128, 0, stream>>>(adj, gw, wd);
  ztr_k<<<B / 64, 256, 0, stream>>>(z, zT, B);
  chain_k<<<R_ * nb, 256, 0, stream>>>(zT, fc_w, fc_b, wd, gb, X, B, nb);
  outer_k<<<B / BBK2, 256, 0, stream>>>(X, out, B);
}

// Round 6
// 139.751 us; speedup vs baseline: 1.8257x; 1.8257x over previous
//
#include <hip/hip_runtime.h>
#include <math.h>

// Problem constants
#define R_ 5
#define NN 68        // N_NODES == LATENT
#define KK 32        // neighbors per node
#define NL 3         // GCN layers
#define LAT 68
#define NSL 17               // nodes per wave slice (4 waves x 17 = 68)
#define ROWQ (NN / 4)        // 17 float4 per node row
#define NF4 ((NN * NN) / 4)  // 1156 float4 per output row
#define BBK2 16              // batches per K2 block
#define LSTR 344             // LDS row stride (floats) for K2, 16B-aligned

// ---------------- P1: densify GCN weights ----------------
// W'[m][n] = sum_{k: adj[n,k]==m} gw[n,k]  (exact rewrite of the gather)
__global__ __launch_bounds__(128) void densify_k(
    const int* __restrict__ adj, const float* __restrict__ gw,
    float* __restrict__ wd) {
  const int rl = blockIdx.x;  // r*NL + l in 0..14
  const int t = threadIdx.x;
  __shared__ float col[NN][NN + 4];
  for (int i = t; i < NN * (NN + 4); i += 128) (&col[0][0])[i] = 0.0f;
  __syncthreads();
  if (t < NN) {
    const int n = t;  // thread owns column n -> no races
    const int* ar = adj + n * KK;
    const float* wr = gw + ((size_t)rl * NN + n) * KK;
    for (int k = 0; k < KK; ++k) col[ar[k]][n] += wr[k];
  }
  __syncthreads();
  float* wout = wd + (size_t)rl * NN * NN;  // [m][n], n contiguous
  for (int i = t; i < NN * NN; i += 128) {
    const int m = i / NN, n = i - m * NN;
    wout[i] = col[m][n];
  }
}

// ---------------- P2: transpose z -> zT[l][b] ----------------
__global__ __launch_bounds__(256) void ztr_k(const float* __restrict__ z,
                                             float* __restrict__ zT, int B) {
  const int t = threadIdx.x;
  const int b0 = blockIdx.x * 64;
  __shared__ float zls[64][LAT + 1];  // +1: stride 69 -> conflict-free both ways
  for (int idx = t; idx < 64 * ROWQ; idx += 256) {
    const int row = idx / ROWQ, q = idx - row * ROWQ;
    const float4 v =
        *reinterpret_cast<const float4*>(z + (size_t)(b0 + row) * LAT + 4 * q);
    zls[row][4 * q + 0] = v.x;
    zls[row][4 * q + 1] = v.y;
    zls[row][4 * q + 2] = v.z;
    zls[row][4 * q + 3] = v.w;
  }
  __syncthreads();
  for (int idx = t; idx < LAT * 64; idx += 256) {
    const int l = idx >> 6, bb = idx & 63;
    zT[(size_t)l * B + b0 + bb] = zls[bb][l];
  }
}

// ---------------- K1: GEMM-chain, 4 waves x 17-node slices ----------------
// Block = (r, 64-batch group), 256 threads. lane = batch. Wave w owns the
// FIXED node slice [17w, 17w+17): slice base forced wave-uniform via
// readfirstlane so ALL weight/bias addresses are scalar -> s_load path.
// 17 SGPRs per weight-row chunk -> compiler can pipeline 2 rows (unroll 2).
// 1280 blocks -> 5 blocks/CU = 20 waves/CU for latency hiding.
__global__ __launch_bounds__(256) void chain_k(
    const float* __restrict__ zT, const float* __restrict__ fc_w,
    const float* __restrict__ fc_b, const float* __restrict__ wd,
    const float* __restrict__ gb, float* __restrict__ X, int B, int nb) {
  const int t = threadIdx.x;
  const int lane = t & 63;
  // wave id, forced into an SGPR so slice addresses are provably uniform
  const int w = __builtin_amdgcn_readfirstlane(t >> 6);
  const int n0 = w * NSL;  // first node of this wave's slice
  const int r = blockIdx.x / nb;
  const int b0 = (blockIdx.x - r * nb) * 64;

  __shared__ float xs[NN][64];  // 17.4 KB; z, then x, per stage

  // stage zT rows for this batch group (coalesced 256B rows)
  for (int idx = t; idx < NN * 64; idx += 256) {
    const int m = idx >> 6;
    xs[m][idx & 63] = zT[(size_t)m * B + b0 + (idx & 63)];
  }
  __syncthreads();

  float acc[NSL];  // statically indexed scalar accumulators

  // ---- 4 stages: fc (no sigmoid), then 3 GCN layers (sigmoid) ----
#pragma unroll 1
  for (int stage = 0; stage < 1 + NL; ++stage) {
    const float* wb = (stage == 0) ? fc_w + (size_t)r * LAT * NN
                                   : wd + (size_t)(r * NL + stage - 1) * NN * NN;
    const float* bias = (stage == 0) ? fc_b + r * NN
                                     : gb + (size_t)(r * NL + stage - 1) * NN;
#pragma unroll
    for (int j = 0; j < NSL; ++j) acc[j] = bias[n0 + j];  // uniform -> s_load

#pragma unroll 2
    for (int m = 0; m < NN; ++m) {
      const float xm = xs[m][lane];          // stride-64, conflict-free
      const float* wr = wb + m * NN + n0;    // wave-uniform -> s_load chunk
#pragma unroll
      for (int j = 0; j < NSL; ++j) acc[j] = fmaf(xm, wr[j], acc[j]);
    }
    if (stage > 0) {
#pragma unroll
      for (int j = 0; j < NSL; ++j)
        acc[j] = 1.0f / (1.0f + __expf(-acc[j]));
    }
    if (stage < NL) {
      __syncthreads();  // everyone done READING xs for this stage
#pragma unroll
      for (int j = 0; j < NSL; ++j) xs[n0 + j][lane] = acc[j];
      __syncthreads();  // new x visible to all waves
    }
  }

  // ---- final X -> ws, layout [r*68+n][b]: coalesced 256B rows ----
  float* Xb = X + ((size_t)r * NN + n0) * B + b0 + lane;
#pragma unroll
  for (int j = 0; j < NSL; ++j) Xb[(size_t)j * B] = acc[j];
}

// ---------------- K2: outer product + store (streaming) ----------------
__global__ __launch_bounds__(256) void outer_k(const float* __restrict__ X,
                                               float* __restrict__ out, int B) {
  const int t = threadIdx.x;
  const int b0 = blockIdx.x * BBK2;
  __shared__ float xls[BBK2 * LSTR];

  // stage X[rn][b0..b0+15] -> xls[bb][rn]; reads are exact 64B lines
  for (int idx = t; idx < R_ * NN * BBK2; idx += 256) {
    const int rn = idx >> 4, bb = idx & (BBK2 - 1);
    xls[bb * LSTR + rn] = X[(size_t)rn * B + b0 + bb];
  }
  __syncthreads();

  float4* ob = reinterpret_cast<float4*>(out) + (size_t)b0 * NF4;
  const int total = BBK2 * NF4;  // 18496
  for (int fg = t; fg < total; fg += 256) {
    const int bb = fg / NF4;
    const int f = fg - bb * NF4;
    const int i = f / ROWQ;
    const int q = f - i * ROWQ;
    const float* xb = &xls[bb * LSTR];
    float4 a = make_float4(0.f, 0.f, 0.f, 0.f);
#pragma unroll
    for (int r = 0; r < R_; ++r) {
      const float xi = xb[r * NN + i];
      const float4 xj = *reinterpret_cast<const float4*>(xb + r * NN + 4 * q);
      a.x = fmaf(xi, xj.x, a.x);
      a.y = fmaf(xi, xj.y, a.y);
      a.z = fmaf(xi, xj.z, a.z);
      a.w = fmaf(xi, xj.w, a.w);
    }
    ob[fg] = a;  // lanes consecutive -> perfectly coalesced
  }
}

extern "C" void kernel_launch(void* const* d_in, const int* in_sizes, int n_in,
                              void* d_out, int out_size, void* d_ws, size_t ws_size,
                              hipStream_t stream) {
  const float* z    = (const float*)d_in[0];  // (16384, 68)
  const int*   adj  = (const int*)  d_in[1];  // (68, 32)
  const float* fc_w = (const float*)d_in[2];  // (5, 68, 68)
  const float* fc_b = (const float*)d_in[3];  // (5, 68)
  const float* gw   = (const float*)d_in[4];  // (5, 3, 68, 32)
  const float* gb   = (const float*)d_in[5];  // (5, 3, 68)
  float* out = (float*)d_out;                 // (16384, 4624)

  const int B = in_sizes[0] / LAT;            // 16384
  // ws layout (f32): wd[15*68*68] | zT[68*B] | X[340*B]  (~27.1 MB total)
  float* wd = (float*)d_ws;
  float* zT = wd + R_ * NL * NN * NN;
  float* X  = zT + (size_t)LAT * B;

  const int nb = B / 64;                      // 256 batch-groups

  densify_k<<<R_ * NL, 128, 0, stream>>>(adj, gw, wd);
  ztr_k<<<B / 64, 256, 0, stream>>>(z, zT, B);
  chain_k<<<R_ * nb, 256, 0, stream>>>(zT, fc_w, fc_b, wd, gb, X, B, nb);
  outer_k<<<B / BBK2, 256, 0, stream>>>(X, out, B);
}